// Round 21
// baseline (117.451 us; speedup 1.0000x reference)
//
#include <hip/hip_runtime.h>

#define NFEAT 64
#define BNODES 64            // nodes per dst-bucket (bucket = dst >> 6)
#define MAXBUCK 1024         // supports N <= 65536 (edge packing needs N <= 65536)
#define SORT_LDS 6144        // whole-bucket LDS staging for in-place sort path
#define KPT 4                // edges per thread in k_part (register-staged)

__device__ __forceinline__ unsigned short f2bf(float f) {
    unsigned int u = __float_as_uint(f);
    return (unsigned short)((u + 0x7FFFu + ((u >> 16) & 1u)) >> 16);
}

// ------- zero bcnt (one tiny block) -----------------------------------------
__global__ void k_zero(int* __restrict__ p, int n) {
    for (int i = threadIdx.x; i < n; i += 1024) p[i] = 0;
}

// ------- bucket-level histogram (782 counters; LDS hist + merge) ------------
__global__ __launch_bounds__(256) void k_histb(
        const int* __restrict__ ei, int* __restrict__ bcnt, int E, int nb) {
    __shared__ int h[MAXBUCK];
    __shared__ int s_not64;
    if (threadIdx.x == 0) s_not64 = 0;
    for (int i = threadIdx.x; i < nb; i += 256) h[i] = 0;
    __syncthreads();
    if (ei[2 * threadIdx.x + 1] != 0) s_not64 = 1;   // benign same-value race
    __syncthreads();
    int is64 = s_not64 ? 0 : 1;
    int per = (E + gridDim.x - 1) / gridDim.x;
    int e0 = blockIdx.x * per;
    int e1 = min(e0 + per, E);
    if (is64) {
        const int2* d64 = (const int2*)ei + E;       // dst half as int2
        for (int i = e0 + threadIdx.x; i < e1; i += 256)
            atomicAdd(&h[d64[i].x >> 6], 1);
    } else {
        for (int i = e0 + threadIdx.x; i < e1; i += 256)
            atomicAdd(&h[ei[E + i] >> 6], 1);
    }
    __syncthreads();
    for (int i = threadIdx.x; i < nb; i += 256)
        if (h[i]) atomicAdd(&bcnt[i], h[i]);
}

// ------- exclusive scan of bucket counts (+ sentinel) ------------------------
__global__ void k_bscan(const int* __restrict__ bcnt, int* __restrict__ bstart,
                        int* __restrict__ bfill, int nb, int E) {
    __shared__ int s[1024];
    int t = threadIdx.x;
    int mine = (t < nb) ? bcnt[t] : 0;
    s[t] = mine;
    __syncthreads();
    for (int off = 1; off < 1024; off <<= 1) {
        int v = (t >= off) ? s[t - off] : 0;
        __syncthreads();
        s[t] += v;
        __syncthreads();
    }
    if (t < nb) {
        int excl = s[t] - mine;
        bstart[t] = excl;
        bfill[t] = excl;
    }
    if (t == 0) bstart[nb] = E;   // sentinel
}

// ------- partition edges into dst-buckets, packed as (dst<<16)|src -----------
__global__ __launch_bounds__(1024) void k_part(
        const int* __restrict__ ei, int* __restrict__ bfill,
        unsigned int* __restrict__ edges, int E, int nb) {
    __shared__ int h[MAXBUCK];
    __shared__ int chunk[MAXBUCK];
    __shared__ int cur[MAXBUCK];
    __shared__ int s_not64;
    if (threadIdx.x == 0) s_not64 = 0;
    for (int i = threadIdx.x; i < nb; i += 1024) h[i] = 0;
    __syncthreads();
    if (threadIdx.x < 256 && ei[2 * threadIdx.x + 1] != 0) s_not64 = 1;
    __syncthreads();
    int is64 = s_not64 ? 0 : 1;
    int per = (E + gridDim.x - 1) / gridDim.x;   // per <= 1024*KPT by grid calc
    int e0 = blockIdx.x * per;
    int e1 = min(e0 + per, E);

    unsigned int ed[KPT];
    if (is64) {
        const int2* s64 = (const int2*)ei;
        const int2* d64 = s64 + E;
#pragma unroll
        for (int k = 0; k < KPT; ++k) {
            int i = e0 + threadIdx.x + k * 1024;
            if (i < e1) {
                unsigned int s = (unsigned int)s64[i].x;
                unsigned int d = (unsigned int)d64[i].x;
                ed[k] = (d << 16) | s;
                atomicAdd(&h[d >> 6], 1);
            }
        }
    } else {
#pragma unroll
        for (int k = 0; k < KPT; ++k) {
            int i = e0 + threadIdx.x + k * 1024;
            if (i < e1) {
                unsigned int s = (unsigned int)ei[i];
                unsigned int d = (unsigned int)ei[E + i];
                ed[k] = (d << 16) | s;
                atomicAdd(&h[d >> 6], 1);
            }
        }
    }
    __syncthreads();
    for (int i = threadIdx.x; i < nb; i += 1024) {
        int c = h[i];
        chunk[i] = c ? atomicAdd(&bfill[i], c) : 0;
        cur[i] = 0;
    }
    __syncthreads();
#pragma unroll
    for (int k = 0; k < KPT; ++k) {
        int i = e0 + threadIdx.x + k * 1024;
        if (i < e1) {
            int b = (int)(ed[k] >> 22);          // = dst >> 6
            int r = atomicAdd(&cur[b], 1);
            edges[chunk[b] + r] = ed[k];
        }
    }
}

// ------- fused: per-bucket counting sort into ushort CSR + count/ptr
//         + per-node factors + y = bf16(dinv * x) ----------------------------
template <bool INPLACE>
__global__ __launch_bounds__(256) void k_sort3(
        const unsigned int* __restrict__ edges, const int* __restrict__ bstart,
        const float* __restrict__ x, int* __restrict__ count,
        int* __restrict__ ptr, float* __restrict__ scale,
        unsigned short* __restrict__ y, unsigned short* __restrict__ sorted_src,
        int N, int E) {
    __shared__ int cnt64[BNODES];
    __shared__ int pos64[BNODES];
    __shared__ unsigned int raw[INPLACE ? SORT_LDS : 1];
    int tid = threadIdx.x;
    int vbase = blockIdx.x * BNODES;
    int es = bstart[blockIdx.x];
    int ee = bstart[blockIdx.x + 1];
    int m = ee - es;
    if (tid < BNODES) cnt64[tid] = 0;
    __syncthreads();

    if (INPLACE) {
        int mm = min(m, SORT_LDS);
        for (int i = tid; i < mm; i += 256) {
            unsigned int e = edges[es + i];
            raw[i] = e;
            atomicAdd(&cnt64[(e >> 16) & 63u], 1);
        }
        for (int i = SORT_LDS + tid; i < m; i += 256)
            atomicAdd(&cnt64[(edges[es + i] >> 16) & 63u], 1);
    } else {
        for (int i = tid; i < m; i += 256)
            atomicAdd(&cnt64[(edges[es + i] >> 16) & 63u], 1);
    }
    __syncthreads();

    if (tid < BNODES) {                      // wave 0: 64-wide exclusive scan
        int c = cnt64[tid];
        int inc = c;
#pragma unroll
        for (int d = 1; d < 64; d <<= 1) {
            int t2 = __shfl_up(inc, d, 64);
            if (tid >= d) inc += t2;
        }
        int off = inc - c;
        pos64[tid] = es + off;
        int v = vbase + tid;
        if (v < N) {
            count[v] = c;
            ptr[v] = es + off;
            float dg = (float)(c + 1);
            scale[v] = rsqrtf(dg) / dg;
        }
    }
    __syncthreads();

    // scatter srcs into CSR
    if (INPLACE) {
        int mm = min(m, SORT_LDS);
        for (int i = tid; i < mm; i += 256) {
            unsigned int e = raw[i];
            int p = atomicAdd(&pos64[(e >> 16) & 63u], 1);
            sorted_src[p] = (unsigned short)(e & 0xFFFFu);
        }
        for (int i = SORT_LDS + tid; i < m; i += 256) {   // overflow: ~never
            unsigned int e = edges[es + i];
            int p = atomicAdd(&pos64[(e >> 16) & 63u], 1);
            sorted_src[p] = (unsigned short)(e & 0xFFFFu);
        }
    } else {
        for (int i = tid; i < m; i += 256) {
            unsigned int e = edges[es + i];
            int p = atomicAdd(&pos64[(e >> 16) & 63u], 1);
            sorted_src[p] = (unsigned short)(e & 0xFFFFu);
        }
    }

    // fused finalize: y rows for this bucket's 64 nodes (coalesced float4)
    const float4* x4 = (const float4*)x;
    for (int i = tid; i < BNODES * 16; i += 256) {
        int r = i >> 4, j = i & 15;
        int v = vbase + r;
        if (v < N) {
            float dg = (float)(cnt64[r] + 1);
            float dv = rsqrtf(dg);
            float4 q = x4[(size_t)v * 16 + j];
            ushort4 o;
            o.x = f2bf(q.x * dv); o.y = f2bf(q.y * dv);
            o.z = f2bf(q.z * dv); o.w = f2bf(q.w * dv);
            ((ushort4*)y)[(size_t)v * 16 + j] = o;
        }
    }
}

// ------- FUSED gather + epilogue ---------------------------------------------
// Block owns 64 consecutive nodes. Phase 1 (R20's packed gather): each of 4
// waves gathers 16 nodes (2 edges/chain slot via lane parity; one dword = 2
// bf16 feats), writing scaled rows DIRECTLY into the padded LDS tile
// (at[r*65+f]: 2-way bank = free). Phase 2 (R16's proven epi6): after one
// __syncthreads, wave w computes columns w*16..+16 for both matrices from the
// LDS tile and stores a full 64B line per lane. Kills the 25.6MB agg
// round-trip, one launch, and the inter-kernel barrier.
__global__ __launch_bounds__(256) void k_gather_epi(
        const unsigned int* __restrict__ y32, const float* __restrict__ scale,
        const int* __restrict__ ptr, const int* __restrict__ count,
        const unsigned short* __restrict__ sorted_src,
        const float* __restrict__ W1, const float* __restrict__ W2,
        float* __restrict__ out, int N) {
    __shared__ float at[64 * 65];
    int tid = threadIdx.x;
    int wave = tid >> 6;
    int lane = tid & 63;
    int lo = lane & 31;          // feature-pair index (feats 2lo, 2lo+1)
    int hi = lane >> 5;          // edge parity
    int vbase = blockIdx.x * 64;

    // ---- phase 1: gather 16 nodes per wave into LDS ----
    for (int vi = 0; vi < 16; ++vi) {
        int v = vbase + wave * 16 + vi;
        if (v < N) {                                   // wave-uniform guard
            int start = ptr[v];
            int cnt = count[v];
            float sc = scale[v];
            float ax0 = 0.f, ay0 = 0.f, ax1 = 0.f, ay1 = 0.f;
            float ax2 = 0.f, ay2 = 0.f, ax3 = 0.f, ay3 = 0.f;
            float ax4 = 0.f, ay4 = 0.f, ax5 = 0.f, ay5 = 0.f;
            float ax6 = 0.f, ay6 = 0.f, ax7 = 0.f, ay7 = 0.f;
            if (hi == 0) {                             // self-loop term
                unsigned int u = y32[(size_t)v * 32 + lo];
                ax0 += __uint_as_float(u << 16);
                ay0 += __uint_as_float(u & 0xFFFF0000u);
            }

#define ACC(AX, AY, E)                                                 \
            {                                                          \
                unsigned int u_ = y32[(size_t)(E) * 32 + lo];          \
                AX += __uint_as_float(u_ << 16);                       \
                AY += __uint_as_float(u_ & 0xFFFF0000u);               \
            }

            for (int c = 0; c < cnt; c += 64) {
                int m = min(64, cnt - c);
                int s_l = 0;
                if (lane < m) s_l = (int)sorted_src[start + c + lane];
                int j = 0;
                for (; j + 16 <= m; j += 16) {
                    int e0 = __shfl(s_l, j + 0 + hi, 64), e1 = __shfl(s_l, j + 2 + hi, 64);
                    int e2 = __shfl(s_l, j + 4 + hi, 64), e3 = __shfl(s_l, j + 6 + hi, 64);
                    int e4 = __shfl(s_l, j + 8 + hi, 64), e5 = __shfl(s_l, j + 10 + hi, 64);
                    int e6 = __shfl(s_l, j + 12 + hi, 64), e7 = __shfl(s_l, j + 14 + hi, 64);
                    ACC(ax0, ay0, e0) ACC(ax1, ay1, e1) ACC(ax2, ay2, e2) ACC(ax3, ay3, e3)
                    ACC(ax4, ay4, e4) ACC(ax5, ay5, e5) ACC(ax6, ay6, e6) ACC(ax7, ay7, e7)
                }
                for (; j + 4 <= m; j += 4) {           // 2 chains x 2 edges
                    int e0 = __shfl(s_l, j + 0 + hi, 64);
                    int e1 = __shfl(s_l, j + 2 + hi, 64);
                    ACC(ax0, ay0, e0) ACC(ax1, ay1, e1)
                }
                for (; j + 2 <= m; j += 2) {           // 1 chain x 2 edges
                    int e0 = __shfl(s_l, j + hi, 64);
                    ACC(ax0, ay0, e0)
                }
                if (j < m) {                           // final odd edge
                    int e0 = __shfl(s_l, j, 64);
                    if (hi == 0) ACC(ax0, ay0, e0)
                }
            }
#undef ACC
            float ax = ((ax0 + ax1) + (ax2 + ax3)) + ((ax4 + ax5) + (ax6 + ax7));
            float ay = ((ay0 + ay1) + (ay2 + ay3)) + ((ay4 + ay5) + (ay6 + ay7));
            ax += __shfl_xor(ax, 32, 64);              // merge edge parity
            ay += __shfl_xor(ay, 32, 64);
            if (hi == 0) {
                int r = wave * 16 + vi;
                at[r * 65 + 2 * lo + 0] = ax * sc;
                at[r * 65 + 2 * lo + 1] = ay * sc;
            }
        }
    }
    __syncthreads();

    // ---- phase 2: epi6 column-slice GEMM from LDS tile ----
    int cb = __builtin_amdgcn_readfirstlane(wave * 16);   // wave-uniform
    float acc1[16], acc2[16];
#pragma unroll
    for (int c = 0; c < 16; ++c) { acc1[c] = 0.f; acc2[c] = 0.f; }

    for (int k = 0; k < NFEAT; ++k) {
        float ak = at[lane * 65 + k];
        const float* w1k = W1 + (size_t)k * NFEAT + cb;
        const float* w2k = W2 + (size_t)k * NFEAT + cb;
#pragma unroll
        for (int c = 0; c < 16; ++c) {
            acc1[c] = fmaf(ak, w1k[c], acc1[c]);
            acc2[c] = fmaf(ak, w2k[c], acc2[c]);
        }
    }

    int v = vbase + lane;
    if (v < N) {
        float4* o4 = (float4*)(out + (size_t)v * NFEAT + cb);
#pragma unroll
        for (int g = 0; g < 4; ++g) {
            float4 q;
            float r0 = fmaxf(acc1[4 * g + 0], 0.f), s0 = 1.f / (1.f + __expf(-acc2[4 * g + 0]));
            float r1 = fmaxf(acc1[4 * g + 1], 0.f), s1 = 1.f / (1.f + __expf(-acc2[4 * g + 1]));
            float r2 = fmaxf(acc1[4 * g + 2], 0.f), s2 = 1.f / (1.f + __expf(-acc2[4 * g + 2]));
            float r3 = fmaxf(acc1[4 * g + 3], 0.f), s3 = 1.f / (1.f + __expf(-acc2[4 * g + 3]));
            q.x = r0 * s0; q.y = r1 * s1; q.z = r2 * s2; q.w = r3 * s3;
            o4[g] = q;
        }
    }
}

extern "C" void kernel_launch(void* const* d_in, const int* in_sizes, int n_in,
                              void* d_out, int out_size, void* d_ws, size_t ws_size,
                              hipStream_t stream) {
    const float* x  = (const float*)d_in[0];
    const int*   ei = (const int*)d_in[1];
    const float* W1 = (const float*)d_in[2];
    const float* W2 = (const float*)d_in[3];
    float* out = (float*)d_out;

    const int N = in_sizes[0] / NFEAT;       // 50000 (<= 65536: edge packing)
    const int E = in_sizes[1] / 2;           // 1,600,000
    const int nb = (N + BNODES - 1) / BNODES;   // 782 buckets

    // workspace layout (256B-aligned slices)
    char* ws = (char*)d_ws;
    size_t off = 0;
    auto alloc = [&](size_t bytes) {
        char* p = ws + off;
        off = (off + bytes + 255) & ~(size_t)255;
        return p;
    };
    int*   count  = (int*)alloc((size_t)N * 4);
    float* scale  = (float*)alloc((size_t)N * 4);
    int*   ptr    = (int*)alloc((size_t)N * 4);
    int*   bcnt   = (int*)alloc((size_t)MAXBUCK * 4);
    int*   bstart = (int*)alloc((size_t)(MAXBUCK + 1) * 4);
    int*   bfill  = (int*)alloc((size_t)MAXBUCK * 4);
    unsigned int*   edges = (unsigned int*)alloc((size_t)E * 4);
    unsigned short* y     = (unsigned short*)alloc((size_t)N * NFEAT * 2);

    // sorted_src: separate if it fits, else alias edges (in-place sort)
    unsigned short* sorted_src;
    bool inplace;
    if (ws_size >= off + (size_t)E * 2) {
        sorted_src = (unsigned short*)alloc((size_t)E * 2);
        inplace = false;
    } else {
        sorted_src = (unsigned short*)edges;
        inplace = true;
    }

    k_zero<<<1, 1024, 0, stream>>>(bcnt, MAXBUCK);
    k_histb<<<256, 256, 0, stream>>>(ei, bcnt, E, nb);
    k_bscan<<<1, 1024, 0, stream>>>(bcnt, bstart, bfill, nb, E);
    int gpart = (E + 1024 * KPT - 1) / (1024 * KPT);
    k_part<<<gpart, 1024, 0, stream>>>(ei, bfill, edges, E, nb);
    if (inplace) {
        k_sort3<true><<<nb, 256, 0, stream>>>(edges, bstart, x, count, ptr,
                                              scale, y, sorted_src, N, E);
    } else {
        k_sort3<false><<<nb, 256, 0, stream>>>(edges, bstart, x, count, ptr,
                                               scale, y, sorted_src, N, E);
    }
    k_gather_epi<<<(N + 63) / 64, 256, 0, stream>>>(
        (const unsigned int*)y, scale, ptr, count, sorted_src, W1, W2, out, N);
}

// Round 22
// 104.552 us; speedup vs baseline: 1.1234x; 1.1234x over previous
//
#include <hip/hip_runtime.h>

#define NFEAT 64
#define BNODES 64            // nodes per dst-bucket (bucket = dst >> 6)
#define MAXBUCK 1024         // supports N <= 65536 (edge packing needs N <= 65536)
#define SORT_LDS 6144        // whole-bucket LDS staging for in-place sort path
#define KPT 4                // edges per thread in k_part (register-staged)

__device__ __forceinline__ unsigned short f2bf(float f) {
    unsigned int u = __float_as_uint(f);
    return (unsigned short)((u + 0x7FFFu + ((u >> 16) & 1u)) >> 16);
}
__device__ __forceinline__ float bf2f(unsigned short h) {
    return __uint_as_float(((unsigned int)h) << 16);
}

// ------- zero bcnt (one tiny block) -----------------------------------------
__global__ void k_zero(int* __restrict__ p, int n) {
    for (int i = threadIdx.x; i < n; i += 1024) p[i] = 0;
}

// ------- bucket-level histogram (782 counters; LDS hist + merge) ------------
__global__ __launch_bounds__(256) void k_histb(
        const int* __restrict__ ei, int* __restrict__ bcnt, int E, int nb) {
    __shared__ int h[MAXBUCK];
    __shared__ int s_not64;
    if (threadIdx.x == 0) s_not64 = 0;
    for (int i = threadIdx.x; i < nb; i += 256) h[i] = 0;
    __syncthreads();
    if (ei[2 * threadIdx.x + 1] != 0) s_not64 = 1;   // benign same-value race
    __syncthreads();
    int is64 = s_not64 ? 0 : 1;
    int per = (E + gridDim.x - 1) / gridDim.x;
    int e0 = blockIdx.x * per;
    int e1 = min(e0 + per, E);
    if (is64) {
        const int2* d64 = (const int2*)ei + E;       // dst half as int2
        for (int i = e0 + threadIdx.x; i < e1; i += 256)
            atomicAdd(&h[d64[i].x >> 6], 1);
    } else {
        for (int i = e0 + threadIdx.x; i < e1; i += 256)
            atomicAdd(&h[ei[E + i] >> 6], 1);
    }
    __syncthreads();
    for (int i = threadIdx.x; i < nb; i += 256)
        if (h[i]) atomicAdd(&bcnt[i], h[i]);
}

// ------- exclusive scan of bucket counts (+ sentinel) ------------------------
__global__ void k_bscan(const int* __restrict__ bcnt, int* __restrict__ bstart,
                        int* __restrict__ bfill, int nb, int E) {
    __shared__ int s[1024];
    int t = threadIdx.x;
    int mine = (t < nb) ? bcnt[t] : 0;
    s[t] = mine;
    __syncthreads();
    for (int off = 1; off < 1024; off <<= 1) {
        int v = (t >= off) ? s[t - off] : 0;
        __syncthreads();
        s[t] += v;
        __syncthreads();
    }
    if (t < nb) {
        int excl = s[t] - mine;
        bstart[t] = excl;
        bfill[t] = excl;
    }
    if (t == 0) bstart[nb] = E;   // sentinel
}

// ------- partition edges into dst-buckets, packed as (dst<<16)|src -----------
__global__ __launch_bounds__(1024) void k_part(
        const int* __restrict__ ei, int* __restrict__ bfill,
        unsigned int* __restrict__ edges, int E, int nb) {
    __shared__ int h[MAXBUCK];
    __shared__ int chunk[MAXBUCK];
    __shared__ int cur[MAXBUCK];
    __shared__ int s_not64;
    if (threadIdx.x == 0) s_not64 = 0;
    for (int i = threadIdx.x; i < nb; i += 1024) h[i] = 0;
    __syncthreads();
    if (threadIdx.x < 256 && ei[2 * threadIdx.x + 1] != 0) s_not64 = 1;
    __syncthreads();
    int is64 = s_not64 ? 0 : 1;
    int per = (E + gridDim.x - 1) / gridDim.x;   // per <= 1024*KPT by grid calc
    int e0 = blockIdx.x * per;
    int e1 = min(e0 + per, E);

    unsigned int ed[KPT];
    if (is64) {
        const int2* s64 = (const int2*)ei;
        const int2* d64 = s64 + E;
#pragma unroll
        for (int k = 0; k < KPT; ++k) {
            int i = e0 + threadIdx.x + k * 1024;
            if (i < e1) {
                unsigned int s = (unsigned int)s64[i].x;
                unsigned int d = (unsigned int)d64[i].x;
                ed[k] = (d << 16) | s;
                atomicAdd(&h[d >> 6], 1);
            }
        }
    } else {
#pragma unroll
        for (int k = 0; k < KPT; ++k) {
            int i = e0 + threadIdx.x + k * 1024;
            if (i < e1) {
                unsigned int s = (unsigned int)ei[i];
                unsigned int d = (unsigned int)ei[E + i];
                ed[k] = (d << 16) | s;
                atomicAdd(&h[d >> 6], 1);
            }
        }
    }
    __syncthreads();
    for (int i = threadIdx.x; i < nb; i += 1024) {
        int c = h[i];
        chunk[i] = c ? atomicAdd(&bfill[i], c) : 0;
        cur[i] = 0;
    }
    __syncthreads();
#pragma unroll
    for (int k = 0; k < KPT; ++k) {
        int i = e0 + threadIdx.x + k * 1024;
        if (i < e1) {
            int b = (int)(ed[k] >> 22);          // = dst >> 6
            int r = atomicAdd(&cur[b], 1);
            edges[chunk[b] + r] = ed[k];
        }
    }
}

// ------- fused: per-bucket counting sort into ushort CSR + count/ptr
//         + per-node factors + y = bf16(dinv * x) ----------------------------
template <bool INPLACE>
__global__ __launch_bounds__(256) void k_sort3(
        const unsigned int* __restrict__ edges, const int* __restrict__ bstart,
        const float* __restrict__ x, int* __restrict__ count,
        int* __restrict__ ptr, float* __restrict__ scale,
        unsigned short* __restrict__ y, unsigned short* __restrict__ sorted_src,
        int N, int E) {
    __shared__ int cnt64[BNODES];
    __shared__ int pos64[BNODES];
    __shared__ unsigned int raw[INPLACE ? SORT_LDS : 1];
    int tid = threadIdx.x;
    int vbase = blockIdx.x * BNODES;
    int es = bstart[blockIdx.x];
    int ee = bstart[blockIdx.x + 1];
    int m = ee - es;
    if (tid < BNODES) cnt64[tid] = 0;
    __syncthreads();

    if (INPLACE) {
        int mm = min(m, SORT_LDS);
        for (int i = tid; i < mm; i += 256) {
            unsigned int e = edges[es + i];
            raw[i] = e;
            atomicAdd(&cnt64[(e >> 16) & 63u], 1);
        }
        for (int i = SORT_LDS + tid; i < m; i += 256)
            atomicAdd(&cnt64[(edges[es + i] >> 16) & 63u], 1);
    } else {
        for (int i = tid; i < m; i += 256)
            atomicAdd(&cnt64[(edges[es + i] >> 16) & 63u], 1);
    }
    __syncthreads();

    if (tid < BNODES) {                      // wave 0: 64-wide exclusive scan
        int c = cnt64[tid];
        int inc = c;
#pragma unroll
        for (int d = 1; d < 64; d <<= 1) {
            int t2 = __shfl_up(inc, d, 64);
            if (tid >= d) inc += t2;
        }
        int off = inc - c;
        pos64[tid] = es + off;
        int v = vbase + tid;
        if (v < N) {
            count[v] = c;
            ptr[v] = es + off;
            float dg = (float)(c + 1);
            scale[v] = rsqrtf(dg) / dg;
        }
    }
    __syncthreads();

    // scatter srcs into CSR
    if (INPLACE) {
        int mm = min(m, SORT_LDS);
        for (int i = tid; i < mm; i += 256) {
            unsigned int e = raw[i];
            int p = atomicAdd(&pos64[(e >> 16) & 63u], 1);
            sorted_src[p] = (unsigned short)(e & 0xFFFFu);
        }
        for (int i = SORT_LDS + tid; i < m; i += 256) {   // overflow: ~never
            unsigned int e = edges[es + i];
            int p = atomicAdd(&pos64[(e >> 16) & 63u], 1);
            sorted_src[p] = (unsigned short)(e & 0xFFFFu);
        }
    } else {
        for (int i = tid; i < m; i += 256) {
            unsigned int e = edges[es + i];
            int p = atomicAdd(&pos64[(e >> 16) & 63u], 1);
            sorted_src[p] = (unsigned short)(e & 0xFFFFu);
        }
    }

    // fused finalize: y rows for this bucket's 64 nodes (coalesced float4)
    const float4* x4 = (const float4*)x;
    for (int i = tid; i < BNODES * 16; i += 256) {
        int r = i >> 4, j = i & 15;
        int v = vbase + r;
        if (v < N) {
            float dg = (float)(cnt64[r] + 1);
            float dv = rsqrtf(dg);
            float4 q = x4[(size_t)v * 16 + j];
            ushort4 o;
            o.x = f2bf(q.x * dv); o.y = f2bf(q.y * dv);
            o.z = f2bf(q.z * dv); o.w = f2bf(q.w * dv);
            ((ushort4*)y)[(size_t)v * 16 + j] = o;
        }
    }
}

// ------- gather v3 (R20 proven): packed-uint loads — one dword = 2 bf16 ------
// feats; 2 edges per chain slot (lanes 0-31 edge j, lanes 32-63 edge j+1).
__global__ __launch_bounds__(256) void k_gather3(
        const unsigned int* __restrict__ y32, const float* __restrict__ scale,
        const int* __restrict__ ptr, const int* __restrict__ count,
        const unsigned short* __restrict__ sorted_src,
        float* __restrict__ agg_out, int N) {
    int wave = threadIdx.x >> 6;
    int lane = threadIdx.x & 63;
    int lo = lane & 31;          // feature-pair index (feats 2lo, 2lo+1)
    int hi = lane >> 5;          // edge parity
    int vbase = blockIdx.x * 16 + wave * 4;

    for (int vi = 0; vi < 4; ++vi) {
        int v = vbase + vi;
        if (v >= N) return;
        int start = ptr[v];
        int cnt = count[v];
        float sc = scale[v];
        float ax0 = 0.f, ay0 = 0.f, ax1 = 0.f, ay1 = 0.f;
        float ax2 = 0.f, ay2 = 0.f, ax3 = 0.f, ay3 = 0.f;
        float ax4 = 0.f, ay4 = 0.f, ax5 = 0.f, ay5 = 0.f;
        float ax6 = 0.f, ay6 = 0.f, ax7 = 0.f, ay7 = 0.f;
        if (hi == 0) {                                 // self-loop term
            unsigned int u = y32[(size_t)v * 32 + lo];
            ax0 += __uint_as_float(u << 16);
            ay0 += __uint_as_float(u & 0xFFFF0000u);
        }

#define ACC(AX, AY, E)                                                 \
        {                                                              \
            unsigned int u_ = y32[(size_t)(E) * 32 + lo];              \
            AX += __uint_as_float(u_ << 16);                           \
            AY += __uint_as_float(u_ & 0xFFFF0000u);                   \
        }

        for (int c = 0; c < cnt; c += 64) {
            int m = min(64, cnt - c);
            int s_l = 0;
            if (lane < m) s_l = (int)sorted_src[start + c + lane];
            int j = 0;
            for (; j + 16 <= m; j += 16) {
                int e0 = __shfl(s_l, j + 0 + hi, 64), e1 = __shfl(s_l, j + 2 + hi, 64);
                int e2 = __shfl(s_l, j + 4 + hi, 64), e3 = __shfl(s_l, j + 6 + hi, 64);
                int e4 = __shfl(s_l, j + 8 + hi, 64), e5 = __shfl(s_l, j + 10 + hi, 64);
                int e6 = __shfl(s_l, j + 12 + hi, 64), e7 = __shfl(s_l, j + 14 + hi, 64);
                ACC(ax0, ay0, e0) ACC(ax1, ay1, e1) ACC(ax2, ay2, e2) ACC(ax3, ay3, e3)
                ACC(ax4, ay4, e4) ACC(ax5, ay5, e5) ACC(ax6, ay6, e6) ACC(ax7, ay7, e7)
            }
            for (; j + 4 <= m; j += 4) {               // 2 chains x 2 edges
                int e0 = __shfl(s_l, j + 0 + hi, 64);
                int e1 = __shfl(s_l, j + 2 + hi, 64);
                ACC(ax0, ay0, e0) ACC(ax1, ay1, e1)
            }
            for (; j + 2 <= m; j += 2) {               // 1 chain x 2 edges
                int e0 = __shfl(s_l, j + hi, 64);
                ACC(ax0, ay0, e0)
            }
            if (j < m) {                               // final odd edge
                int e0 = __shfl(s_l, j, 64);
                if (hi == 0) ACC(ax0, ay0, e0)
            }
        }
#undef ACC
        float ax = ((ax0 + ax1) + (ax2 + ax3)) + ((ax4 + ax5) + (ax6 + ax7));
        float ay = ((ay0 + ay1) + (ay2 + ay3)) + ((ay4 + ay5) + (ay6 + ay7));
        ax += __shfl_xor(ax, 32, 64);                  // merge edge parity
        ay += __shfl_xor(ay, 32, 64);
        if (hi == 0) {
            float2 st;
            st.x = ax * sc;
            st.y = ay * sc;
            ((float2*)(agg_out + (size_t)v * NFEAT))[lo] = st;
        }
    }
}

// ------- epilogue v6 (R16 proven): LDS a-tile, lane = node, wave = 16 cols ---
__global__ __launch_bounds__(256) void k_epi6(
        const float* __restrict__ agg, const float* __restrict__ W1,
        const float* __restrict__ W2, float* __restrict__ out, int N) {
    __shared__ float at[64 * 65];
    int tid = threadIdx.x;
    int lane = tid & 63;
    int v0 = blockIdx.x * 64;

    const float4* agg4 = (const float4*)agg;
    for (int i = tid; i < 64 * 16; i += 256) {
        int v = i >> 4, j = i & 15;
        float4 q;
        if (v0 + v < N) q = agg4[(size_t)(v0 + v) * 16 + j];
        else { q.x = q.y = q.z = q.w = 0.f; }
        float* r = &at[v * 65 + j * 4];
        r[0] = q.x; r[1] = q.y; r[2] = q.z; r[3] = q.w;
    }
    __syncthreads();

    int cb = __builtin_amdgcn_readfirstlane((tid >> 6) * 16);   // wave-uniform
    float acc1[16], acc2[16];
#pragma unroll
    for (int c = 0; c < 16; ++c) { acc1[c] = 0.f; acc2[c] = 0.f; }

    for (int k = 0; k < NFEAT; ++k) {
        float ak = at[lane * 65 + k];
        const float* w1k = W1 + (size_t)k * NFEAT + cb;
        const float* w2k = W2 + (size_t)k * NFEAT + cb;
#pragma unroll
        for (int c = 0; c < 16; ++c) {
            acc1[c] = fmaf(ak, w1k[c], acc1[c]);
            acc2[c] = fmaf(ak, w2k[c], acc2[c]);
        }
    }

    int v = v0 + lane;
    if (v < N) {
        float4* o4 = (float4*)(out + (size_t)v * NFEAT + cb);
#pragma unroll
        for (int g = 0; g < 4; ++g) {
            float4 q;
            float r0 = fmaxf(acc1[4 * g + 0], 0.f), s0 = 1.f / (1.f + __expf(-acc2[4 * g + 0]));
            float r1 = fmaxf(acc1[4 * g + 1], 0.f), s1 = 1.f / (1.f + __expf(-acc2[4 * g + 1]));
            float r2 = fmaxf(acc1[4 * g + 2], 0.f), s2 = 1.f / (1.f + __expf(-acc2[4 * g + 2]));
            float r3 = fmaxf(acc1[4 * g + 3], 0.f), s3 = 1.f / (1.f + __expf(-acc2[4 * g + 3]));
            q.x = r0 * s0; q.y = r1 * s1; q.z = r2 * s2; q.w = r3 * s3;
            o4[g] = q;
        }
    }
}

extern "C" void kernel_launch(void* const* d_in, const int* in_sizes, int n_in,
                              void* d_out, int out_size, void* d_ws, size_t ws_size,
                              hipStream_t stream) {
    const float* x  = (const float*)d_in[0];
    const int*   ei = (const int*)d_in[1];
    const float* W1 = (const float*)d_in[2];
    const float* W2 = (const float*)d_in[3];
    float* out = (float*)d_out;

    const int N = in_sizes[0] / NFEAT;       // 50000 (<= 65536: edge packing)
    const int E = in_sizes[1] / 2;           // 1,600,000
    const int nb = (N + BNODES - 1) / BNODES;   // 782 buckets

    // workspace layout (256B-aligned slices)
    char* ws = (char*)d_ws;
    size_t off = 0;
    auto alloc = [&](size_t bytes) {
        char* p = ws + off;
        off = (off + bytes + 255) & ~(size_t)255;
        return p;
    };
    int*   count  = (int*)alloc((size_t)N * 4);
    float* scale  = (float*)alloc((size_t)N * 4);
    int*   ptr    = (int*)alloc((size_t)N * 4);
    int*   bcnt   = (int*)alloc((size_t)MAXBUCK * 4);
    int*   bstart = (int*)alloc((size_t)(MAXBUCK + 1) * 4);
    int*   bfill  = (int*)alloc((size_t)MAXBUCK * 4);

    size_t aggB   = (size_t)N * NFEAT * 4;
    size_t edgeB  = (size_t)E * 4;
    size_t regB   = aggB > edgeB ? aggB : edgeB;
    size_t t1_need = off + regB + (size_t)N * NFEAT * 2 + (size_t)E * 2 + 1024;

    k_zero<<<1, 1024, 0, stream>>>(bcnt, MAXBUCK);
    k_histb<<<256, 256, 0, stream>>>(ei, bcnt, E, nb);
    k_bscan<<<1, 1024, 0, stream>>>(bcnt, bstart, bfill, nb, E);
    int gpart = (E + 1024 * KPT - 1) / (1024 * KPT);
    int gblk = (N + 15) / 16;

    if (ws_size >= t1_need) {
        // ---- T1: separate agg + CSR; fused sort+finalize; packed gather ----
        char* reg = (char*)alloc(regB);
        unsigned int*   edges      = (unsigned int*)reg;
        float*          agg        = (float*)reg;
        unsigned short* y          = (unsigned short*)alloc((size_t)N * NFEAT * 2);
        unsigned short* sorted_src = (unsigned short*)alloc((size_t)E * 2);

        k_part<<<gpart, 1024, 0, stream>>>(ei, bfill, edges, E, nb);
        k_sort3<false><<<nb, 256, 0, stream>>>(edges, bstart, x, count, ptr,
                                               scale, y, sorted_src, N, E);
        k_gather3<<<gblk, 256, 0, stream>>>((const unsigned int*)y, scale, ptr,
                                            count, sorted_src, agg, N);
        k_epi6<<<(N + 63) / 64, 256, 0, stream>>>(agg, W1, W2, out, N);
    } else {
        // ---- T2: fallback — agg in d_out scratch, in-place sort, same epi --
        unsigned int*   edges = (unsigned int*)alloc(edgeB);
        unsigned short* y     = (unsigned short*)alloc((size_t)N * NFEAT * 2);
        unsigned short* sorted_src;
        bool inplace;
        if (ws_size >= off + (size_t)E * 2) {
            sorted_src = (unsigned short*)alloc((size_t)E * 2);
            inplace = false;
        } else {
            sorted_src = (unsigned short*)edges;
            inplace = true;
        }
        k_part<<<gpart, 1024, 0, stream>>>(ei, bfill, edges, E, nb);
        if (inplace) {
            k_sort3<true><<<nb, 256, 0, stream>>>(edges, bstart, x, count, ptr,
                                                  scale, y, sorted_src, N, E);
        } else {
            k_sort3<false><<<nb, 256, 0, stream>>>(edges, bstart, x, count, ptr,
                                                   scale, y, sorted_src, N, E);
        }
        k_gather3<<<gblk, 256, 0, stream>>>((const unsigned int*)y, scale, ptr,
                                            count, sorted_src, out, N);
        k_epi6<<<(N + 63) / 64, 256, 0, stream>>>(out, W1, W2, out, N);
    }
}